// Round 5
// baseline (408.897 us; speedup 1.0000x reference)
//
#include <hip/hip_runtime.h>

// Masked MSE: out = sum((in-tgt)^2 * (mask==1)) / sum(mask==1)
// Memory-bound 3-stream read reduction (302 MB, no reuse).
// R4 evidence: L3-resident replay runs at the SAME speed as HBM-sourced
// (89 us, 3.39 TB/s combined) -> limiter is the consumer-side read path,
// not HBM. R5 test: raise CU-level load concurrency (occupancy 42% -> ~full)
// with 8192 blocks x UNROLL=3 staged nt loads. If neutral -> read-path
// roofline (~3.3-3.4 TB/s, matching m13 copy's read component).

#define BLOCK 256
#define UNROLL 3

typedef float vfloat4 __attribute__((ext_vector_type(4)));
typedef int   vint4   __attribute__((ext_vector_type(4)));

__global__ __launch_bounds__(BLOCK) void masked_mse_reduce(
    const vfloat4* __restrict__ inp,
    const vfloat4* __restrict__ tgt,
    const vint4* __restrict__ msk,
    float* __restrict__ acc_sum,
    unsigned int* __restrict__ acc_cnt)
{
    const long base = (long)blockIdx.x * (BLOCK * UNROLL) + threadIdx.x;

    vfloat4 a[UNROLL];
    vfloat4 b[UNROLL];
    vint4 m[UNROLL];
#pragma unroll
    for (int u = 0; u < UNROLL; ++u) {
        const long i = base + (long)u * BLOCK;   // wave-coalesced per u
        a[u] = __builtin_nontemporal_load(&inp[i]);
        b[u] = __builtin_nontemporal_load(&tgt[i]);
        m[u] = __builtin_nontemporal_load(&msk[i]);
    }

    float s = 0.0f;
    unsigned int c = 0u;
#pragma unroll
    for (int u = 0; u < UNROLL; ++u) {
        float d0 = a[u].x - b[u].x;
        float d1 = a[u].y - b[u].y;
        float d2 = a[u].z - b[u].z;
        float d3 = a[u].w - b[u].w;
        s += (float)m[u].x * d0 * d0;
        s += (float)m[u].y * d1 * d1;
        s += (float)m[u].z * d2 * d2;
        s += (float)m[u].w * d3 * d3;
        c += (unsigned int)(m[u].x + m[u].y + m[u].z + m[u].w);
    }

    // wave-64 shuffle reduction
#pragma unroll
    for (int off = 32; off > 0; off >>= 1) {
        s += __shfl_down(s, off, 64);
        c += __shfl_down(c, off, 64);
    }

    __shared__ float ssum[BLOCK / 64];
    __shared__ unsigned int scnt[BLOCK / 64];
    const int lane = threadIdx.x & 63;
    const int wave = threadIdx.x >> 6;
    if (lane == 0) {
        ssum[wave] = s;
        scnt[wave] = c;
    }
    __syncthreads();
    if (threadIdx.x == 0) {
        float bs = 0.0f;
        unsigned int bc = 0u;
#pragma unroll
        for (int w = 0; w < BLOCK / 64; ++w) {
            bs += ssum[w];
            bc += scnt[w];
        }
        atomicAdd(acc_sum, bs);
        atomicAdd(acc_cnt, bc);
    }
}

// Tail for non-divisible sizes (none for the reference shape).
__global__ void masked_mse_tail(
    const float* __restrict__ inp,
    const float* __restrict__ tgt,
    const int* __restrict__ msk,
    float* __restrict__ acc_sum,
    unsigned int* __restrict__ acc_cnt,
    long start, long n)
{
    long i = start + blockIdx.x * (long)blockDim.x + threadIdx.x;
    float s = 0.0f;
    unsigned int c = 0u;
    for (; i < n; i += (long)gridDim.x * blockDim.x) {
        float d = inp[i] - tgt[i];
        int mv = msk[i];
        s += (float)mv * d * d;
        c += (unsigned int)mv;
    }
#pragma unroll
    for (int off = 32; off > 0; off >>= 1) {
        s += __shfl_down(s, off, 64);
        c += __shfl_down(c, off, 64);
    }
    if ((threadIdx.x & 63) == 0) {
        atomicAdd(acc_sum, s);
        atomicAdd(acc_cnt, c);
    }
}

__global__ void masked_mse_finalize(const float* __restrict__ acc_sum,
                                    const unsigned int* __restrict__ acc_cnt,
                                    float* __restrict__ out)
{
    out[0] = acc_sum[0] / (float)acc_cnt[0];
}

extern "C" void kernel_launch(void* const* d_in, const int* in_sizes, int n_in,
                              void* d_out, int out_size, void* d_ws, size_t ws_size,
                              hipStream_t stream)
{
    const float* inp = (const float*)d_in[0];
    const float* tgt = (const float*)d_in[1];
    const int* msk = (const int*)d_in[2];
    const long n = in_sizes[0];
    const long n4 = n / 4;

    float* acc_sum = (float*)d_ws;
    unsigned int* acc_cnt = (unsigned int*)((char*)d_ws + sizeof(float));

    (void)hipMemsetAsync(d_ws, 0, 2 * sizeof(float), stream);

    const long per_block = (long)BLOCK * UNROLL;     // float4s per block
    const long nblocks = n4 / per_block;             // 8192 for reference shape
    if (nblocks > 0) {
        masked_mse_reduce<<<(int)nblocks, BLOCK, 0, stream>>>(
            (const vfloat4*)inp, (const vfloat4*)tgt, (const vint4*)msk,
            acc_sum, acc_cnt);
    }
    const long covered = nblocks * per_block * 4;
    if (covered < n) {
        masked_mse_tail<<<64, BLOCK, 0, stream>>>(
            inp, tgt, msk, acc_sum, acc_cnt, covered, n);
    }
    masked_mse_finalize<<<1, 1, 0, stream>>>(acc_sum, acc_cnt, (float*)d_out);
}

// Round 6
// 248.466 us; speedup vs baseline: 1.6457x; 1.6457x over previous
//
#include <hip/hip_runtime.h>

// Masked MSE: out = sum((in-tgt)^2 * (mask==1)) / sum(mask==1)
// Memory-bound 3-stream read reduction (302 MB, no reuse).
//
// R5 insight: runtime across R1-R5 tracks per-block atomic count at
// ~13-15 ns/atomic -- all blocks hit the SAME cache line (acc_sum/acc_cnt),
// serializing at one L2 bank. This also explains why R4's L3-resident
// replay ran at identical speed (atomic drain was the floor, not reads).
// R6: two-stage reduction, zero same-address atomics. Stage 1 stores each
// block's partial to its own slot; stage 2 (1 block) reduces 3072 partials.

#define BLOCK 256
#define UNROLL 8
#define MAX_PARTS 8192          // capacity for partials in d_ws (64 KB used)

typedef float vfloat4 __attribute__((ext_vector_type(4)));
typedef int   vint4   __attribute__((ext_vector_type(4)));

__global__ __launch_bounds__(BLOCK, 2) void masked_mse_stage1(
    const vfloat4* __restrict__ inp,
    const vfloat4* __restrict__ tgt,
    const vint4* __restrict__ msk,
    float* __restrict__ part_sum,
    unsigned int* __restrict__ part_cnt)
{
    const long base = (long)blockIdx.x * (BLOCK * UNROLL) + threadIdx.x;

    vfloat4 a[UNROLL];
    vfloat4 b[UNROLL];
    vint4 m[UNROLL];
#pragma unroll
    for (int u = 0; u < UNROLL; ++u) {
        const long i = base + (long)u * BLOCK;   // wave-coalesced per u
        a[u] = __builtin_nontemporal_load(&inp[i]);
        b[u] = __builtin_nontemporal_load(&tgt[i]);
        m[u] = __builtin_nontemporal_load(&msk[i]);
    }

    float s = 0.0f;
    unsigned int c = 0u;
#pragma unroll
    for (int u = 0; u < UNROLL; ++u) {
        float d0 = a[u].x - b[u].x;
        float d1 = a[u].y - b[u].y;
        float d2 = a[u].z - b[u].z;
        float d3 = a[u].w - b[u].w;
        s += (float)m[u].x * d0 * d0;
        s += (float)m[u].y * d1 * d1;
        s += (float)m[u].z * d2 * d2;
        s += (float)m[u].w * d3 * d3;
        c += (unsigned int)(m[u].x + m[u].y + m[u].z + m[u].w);
    }

    // wave-64 shuffle reduction
#pragma unroll
    for (int off = 32; off > 0; off >>= 1) {
        s += __shfl_down(s, off, 64);
        c += __shfl_down(c, off, 64);
    }

    __shared__ float ssum[BLOCK / 64];
    __shared__ unsigned int scnt[BLOCK / 64];
    const int lane = threadIdx.x & 63;
    const int wave = threadIdx.x >> 6;
    if (lane == 0) {
        ssum[wave] = s;
        scnt[wave] = c;
    }
    __syncthreads();
    if (threadIdx.x == 0) {
        float bs = 0.0f;
        unsigned int bc = 0u;
#pragma unroll
        for (int w = 0; w < BLOCK / 64; ++w) {
            bs += ssum[w];
            bc += scnt[w];
        }
        // contention-free: each block owns its slot
        part_sum[blockIdx.x] = bs;
        part_cnt[blockIdx.x] = bc;
    }
}

// Tail for non-divisible sizes (none for the reference shape).
// Writes partials to slots [tail_base, tail_base+gridDim.x).
__global__ void masked_mse_tail(
    const float* __restrict__ inp,
    const float* __restrict__ tgt,
    const int* __restrict__ msk,
    float* __restrict__ part_sum,
    unsigned int* __restrict__ part_cnt,
    long start, long n, int tail_base)
{
    long i = start + blockIdx.x * (long)blockDim.x + threadIdx.x;
    float s = 0.0f;
    unsigned int c = 0u;
    for (; i < n; i += (long)gridDim.x * blockDim.x) {
        float d = inp[i] - tgt[i];
        int mv = msk[i];
        s += (float)mv * d * d;
        c += (unsigned int)mv;
    }
#pragma unroll
    for (int off = 32; off > 0; off >>= 1) {
        s += __shfl_down(s, off, 64);
        c += __shfl_down(c, off, 64);
    }
    __shared__ float ssum[4];
    __shared__ unsigned int scnt[4];
    const int lane = threadIdx.x & 63;
    const int wave = threadIdx.x >> 6;
    if (lane == 0) { ssum[wave] = s; scnt[wave] = c; }
    __syncthreads();
    if (threadIdx.x == 0) {
        float bs = 0.0f;
        unsigned int bc = 0u;
        for (int w = 0; w < (int)(blockDim.x / 64); ++w) { bs += ssum[w]; bc += scnt[w]; }
        part_sum[tail_base + blockIdx.x] = bs;
        part_cnt[tail_base + blockIdx.x] = bc;
    }
}

__global__ __launch_bounds__(1024) void masked_mse_stage2(
    const float* __restrict__ part_sum,
    const unsigned int* __restrict__ part_cnt,
    int nparts,
    float* __restrict__ out)
{
    float s = 0.0f;
    unsigned int c = 0u;
    for (int i = threadIdx.x; i < nparts; i += blockDim.x) {
        s += part_sum[i];
        c += part_cnt[i];
    }
#pragma unroll
    for (int off = 32; off > 0; off >>= 1) {
        s += __shfl_down(s, off, 64);
        c += __shfl_down(c, off, 64);
    }
    __shared__ float ssum[16];
    __shared__ unsigned int scnt[16];
    const int lane = threadIdx.x & 63;
    const int wave = threadIdx.x >> 6;
    if (lane == 0) { ssum[wave] = s; scnt[wave] = c; }
    __syncthreads();
    if (threadIdx.x == 0) {
        float ts = 0.0f;
        unsigned int tc = 0u;
#pragma unroll
        for (int w = 0; w < 16; ++w) { ts += ssum[w]; tc += scnt[w]; }
        out[0] = ts / (float)tc;
    }
}

extern "C" void kernel_launch(void* const* d_in, const int* in_sizes, int n_in,
                              void* d_out, int out_size, void* d_ws, size_t ws_size,
                              hipStream_t stream)
{
    const float* inp = (const float*)d_in[0];
    const float* tgt = (const float*)d_in[1];
    const int* msk = (const int*)d_in[2];
    const long n = in_sizes[0];
    const long n4 = n / 4;

    float* part_sum = (float*)d_ws;
    unsigned int* part_cnt = (unsigned int*)((char*)d_ws + MAX_PARTS * sizeof(float));

    const long per_block = (long)BLOCK * UNROLL;     // float4s per block
    long nblocks = n4 / per_block;                   // 3072 for reference shape
    if (nblocks > MAX_PARTS - 64) nblocks = MAX_PARTS - 64;  // clamp (generality)

    int nparts = 0;
    if (nblocks > 0) {
        masked_mse_stage1<<<(int)nblocks, BLOCK, 0, stream>>>(
            (const vfloat4*)inp, (const vfloat4*)tgt, (const vint4*)msk,
            part_sum, part_cnt);
        nparts = (int)nblocks;
    }
    const long covered = nblocks * per_block * 4;    // elements covered
    if (covered < n) {
        masked_mse_tail<<<64, BLOCK, 0, stream>>>(
            inp, tgt, msk, part_sum, part_cnt, covered, n, nparts);
        nparts += 64;
    }
    masked_mse_stage2<<<1, 1024, 0, stream>>>(part_sum, part_cnt, nparts, (float*)d_out);
}